// Round 4
// baseline (738.268 us; speedup 1.0000x reference)
//
#include <hip/hip_runtime.h>
#include <math.h>

#define N_NODES 40000
#define N_EDGES 640000
#define HID 128
#define MAXW 64      // in-degree ~ Poisson(16); P(deg > 64) ~ 1e-19 -> never drops edges
#define ITERS 8      // full iterations after initial state = tanh(xproj)
#define NH (N_NODES * HID)

typedef __bf16 bf16x8 __attribute__((ext_vector_type(8)));
typedef __bf16 bf16x4 __attribute__((ext_vector_type(4)));
typedef float floatx4 __attribute__((ext_vector_type(4)));

// Fill ELL with pad index N_NODES, zero deg, zero the pad row of BOTH state buffers.
__global__ __launch_bounds__(256) void init_kernel(int* __restrict__ ell,
                                                   int* __restrict__ deg,
                                                   __bf16* __restrict__ padA,
                                                   __bf16* __restrict__ padB) {
    int i = blockIdx.x * 256 + threadIdx.x;   // N_EDGES threads
    int4 pad = {N_NODES, N_NODES, N_NODES, N_NODES};
    ((int4*)ell)[i] = pad;                    // N*MAXW/4 = 640000 int4 exactly
    if (i < N_NODES) deg[i] = 0;
    if (i < HID / 8) {
        bf16x8 z;
#pragma unroll
        for (int j = 0; j < 8; ++j) z[j] = (__bf16)0.f;
        ((bf16x8*)padA)[i] = z;
        ((bf16x8*)padB)[i] = z;
    }
}

__global__ __launch_bounds__(256) void build_ell_kernel(const int* __restrict__ ei,
                                                        int* __restrict__ deg,
                                                        int* __restrict__ ell) {
    int e = blockIdx.x * 256 + threadIdx.x;
    if (e >= N_EDGES) return;
    int s = ei[e];            // src
    int d = ei[N_EDGES + e];  // dst
    int c = atomicAdd(&deg[d], 1);
    if (c < MAXW) ell[d * MAXW + c] = s;
}

// Pack W (or W^T) into B-fragment order for mfma_f32_16x16x32_bf16:
// pk[((c*8+t)*64 + lane)*8 + j] = B[k = c*32 + (lane>>4)*8 + j][n = t*16 + (lane&15)]
__global__ __launch_bounds__(256) void pack_w_kernel(const float* __restrict__ w,
                                                     __bf16* __restrict__ pk, int trans) {
    int f = blockIdx.x * 256 + threadIdx.x;  // 16384 total
    int j = f & 7, l = (f >> 3) & 63, t = (f >> 9) & 7, c = f >> 12;
    int k = c * 32 + (l >> 4) * 8 + j;
    int n = t * 16 + (l & 15);
    float v = trans ? w[n * HID + k] : w[k * HID + n];
    pk[f] = (__bf16)v;
}

__global__ __launch_bounds__(256) void cast_bf16_kernel(const float* __restrict__ x,
                                                        __bf16* __restrict__ o) {
    int i = blockIdx.x * 256 + threadIdx.x;   // NH/4 threads
    float4 v = ((const float4*)x)[i];
    bf16x4 b;
    b[0] = (__bf16)v.x; b[1] = (__bf16)v.y; b[2] = (__bf16)v.z; b[3] = (__bf16)v.w;
    ((bf16x4*)o)[i] = b;
}

// Standalone GEMM for the xproj step: out = A @ B (+tanh state). Same as round 3.
__global__ __launch_bounds__(256) void mfma_gemm_kernel(const __bf16* A,
                                                        const __bf16* __restrict__ Bpk,
                                                        float* __restrict__ raw_out,
                                                        __bf16* st_bf) {
    __shared__ float tile[4][16][132];
    int tid = threadIdx.x;
    int wv = tid >> 6, lane = tid & 63;
    int q = lane >> 4, cl = lane & 15;

    int row_a = blockIdx.x * 64 + wv * 16 + cl;
    bf16x8 a[4];
#pragma unroll
    for (int c = 0; c < 4; ++c)
        a[c] = *(const bf16x8*)(A + (size_t)row_a * HID + c * 32 + q * 8);

#pragma unroll
    for (int t = 0; t < 8; ++t) {
        floatx4 acc_t = {0.f, 0.f, 0.f, 0.f};
#pragma unroll
        for (int c = 0; c < 4; ++c) {
            bf16x8 b = *(const bf16x8*)(Bpk + (((c * 8 + t) * 64 + lane) << 3));
            acc_t = __builtin_amdgcn_mfma_f32_16x16x32_bf16(a[c], b, acc_t, 0, 0, 0);
        }
#pragma unroll
        for (int r = 0; r < 4; ++r)
            tile[wv][q * 4 + r][t * 16 + cl] = acc_t[r];
    }
    int row = lane >> 2, seg = lane & 3;
    size_t goff = (size_t)(blockIdx.x * 64 + wv * 16 + row) * HID + seg * 32;
    float v[32];
#pragma unroll
    for (int j = 0; j < 8; ++j) {
        floatx4 t4 = *(floatx4*)&tile[wv][row][seg * 32 + j * 4];
        v[j * 4] = t4[0]; v[j * 4 + 1] = t4[1]; v[j * 4 + 2] = t4[2]; v[j * 4 + 3] = t4[3];
        float4 o = {t4[0], t4[1], t4[2], t4[3]};
        *(float4*)(raw_out + goff + j * 4) = o;   // xproj (pre-tanh)
    }
#pragma unroll
    for (int i = 0; i < 32; ++i) v[i] = tanhf(v[i]);
#pragma unroll
    for (int j = 0; j < 4; ++j) {
        bf16x8 o;
#pragma unroll
        for (int k = 0; k < 8; ++k) o[k] = (__bf16)v[j * 8 + k];
        *(bf16x8*)(st_bf + goff + j * 8) = o;
    }
}

// Fused iteration: state_out = tanh(xproj + gather(state_in) @ W).
// Phase 1: each wave aggregates 16 nodes into LDS (quarter-wave gather, 4
//   outstanding 16B loads/lane, ELL idx rows preloaded for MLP).
// Phase 2: MFMA consumes the LDS aggr tile directly (A-frag ds_read_b128,
//   row pad 136 bf16 -> 2-way banking = free), epilogue = round-3 scheme.
// aggr never touches global memory; state double-buffered so no cross-block race.
// LDS: aggr region (17408 B) overlaid with epilogue tile (33792 B); barrier
// after frag loads makes the overlay safe. 33.8 KB -> 4 blocks/CU.
__global__ __launch_bounds__(256) void fused_iter_kernel(
    const __bf16* __restrict__ state_in,
    __bf16* __restrict__ state_out,
    const int* __restrict__ ell,
    const int* __restrict__ deg,
    const __bf16* __restrict__ Bpk,
    const float* __restrict__ xproj,
    float* __restrict__ st_f32) {
    __shared__ __align__(16) char smem[33792];
    __bf16(*aggr_lds)[136] = (__bf16(*)[136])smem;   // [64][136] bf16 = 17408 B
    float(*tile)[16][132] = (float(*)[16][132])smem; // [4][16][132] f32 = 33792 B

    int tid = threadIdx.x;
    int wv = tid >> 6, lane = tid & 63;
    int q = lane >> 4, f = lane & 15;
    int nodebase = blockIdx.x * 64 + wv * 16;

    // ---- phase 1: gather 16 nodes into LDS ----
    int degv = deg[nodebase + (lane & 15)];
    int myidx[16];
#pragma unroll
    for (int nl = 0; nl < 16; ++nl)
        myidx[nl] = ell[(nodebase + nl) * MAXW + lane];

#pragma unroll
    for (int nl = 0; nl < 16; ++nl) {
        int cnt = __shfl(degv, nl);
        if (cnt > MAXW) cnt = MAXW;
        float acc[8];
#pragma unroll
        for (int j = 0; j < 8; ++j) acc[j] = 0.f;
        int iters = (cnt + 3) >> 2;
        for (int i0 = 0; i0 < iters; i0 += 4) {
            int base = i0 * 4 + q;
            int s0 = __shfl(myidx[nl], base);
            int s1 = __shfl(myidx[nl], base + 4);
            int s2 = __shfl(myidx[nl], base + 8);
            int s3 = __shfl(myidx[nl], base + 12);
            bf16x8 v0 = *(const bf16x8*)(state_in + (size_t)s0 * HID + f * 8);
            bf16x8 v1 = *(const bf16x8*)(state_in + (size_t)s1 * HID + f * 8);
            bf16x8 v2 = *(const bf16x8*)(state_in + (size_t)s2 * HID + f * 8);
            bf16x8 v3 = *(const bf16x8*)(state_in + (size_t)s3 * HID + f * 8);
#pragma unroll
            for (int j = 0; j < 8; ++j)
                acc[j] += ((float)v0[j] + (float)v1[j]) + ((float)v2[j] + (float)v3[j]);
        }
#pragma unroll
        for (int j = 0; j < 8; ++j) {
            acc[j] += __shfl_xor(acc[j], 16);
            acc[j] += __shfl_xor(acc[j], 32);
        }
        if (q == 0) {
            bf16x8 o;
#pragma unroll
            for (int j = 0; j < 8; ++j) o[j] = (__bf16)acc[j];
            *(bf16x8*)&aggr_lds[wv * 16 + nl][f * 8] = o;
        }
    }
    __syncthreads();

    // ---- phase 2: A-frags from LDS, then free the aggr region for the tile ----
    int cl = lane & 15;
    bf16x8 a[4];
#pragma unroll
    for (int c = 0; c < 4; ++c)
        a[c] = *(const bf16x8*)&aggr_lds[wv * 16 + cl][c * 32 + q * 8];
    __syncthreads();   // overlay safety: all frag reads done before tile writes

#pragma unroll
    for (int t = 0; t < 8; ++t) {
        floatx4 acc_t = {0.f, 0.f, 0.f, 0.f};
#pragma unroll
        for (int c = 0; c < 4; ++c) {
            bf16x8 b = *(const bf16x8*)(Bpk + (((c * 8 + t) * 64 + lane) << 3));
            acc_t = __builtin_amdgcn_mfma_f32_16x16x32_bf16(a[c], b, acc_t, 0, 0, 0);
        }
#pragma unroll
        for (int r = 0; r < 4; ++r)
            tile[wv][q * 4 + r][t * 16 + cl] = acc_t[r];
    }

    int row = lane >> 2, seg = lane & 3;
    size_t goff = (size_t)(blockIdx.x * 64 + wv * 16 + row) * HID + seg * 32;
    float v[32];
#pragma unroll
    for (int j = 0; j < 8; ++j) {
        floatx4 t4 = *(floatx4*)&tile[wv][row][seg * 32 + j * 4];
        float4 b = *(const float4*)(xproj + goff + j * 4);
        v[j * 4] = t4[0] + b.x;
        v[j * 4 + 1] = t4[1] + b.y;
        v[j * 4 + 2] = t4[2] + b.z;
        v[j * 4 + 3] = t4[3] + b.w;
    }
#pragma unroll
    for (int i = 0; i < 32; ++i) v[i] = tanhf(v[i]);
#pragma unroll
    for (int j = 0; j < 4; ++j) {
        bf16x8 o;
#pragma unroll
        for (int k = 0; k < 8; ++k) o[k] = (__bf16)v[j * 8 + k];
        *(bf16x8*)(state_out + goff + j * 8) = o;
    }
    if (st_f32) {
#pragma unroll
        for (int j = 0; j < 8; ++j) {
            float4 o = {v[j * 4], v[j * 4 + 1], v[j * 4 + 2], v[j * 4 + 3]};
            *(float4*)(st_f32 + goff + j * 4) = o;
        }
    }
}

extern "C" void kernel_launch(void* const* d_in, const int* in_sizes, int n_in,
                              void* d_out, int out_size, void* d_ws, size_t ws_size,
                              hipStream_t stream) {
    const int* ei = (const int*)d_in[0];       // edge_index [2][E]
    const float* x = (const float*)d_in[1];    // [N][128] f32
    const float* w_in0 = (const float*)d_in[2];
    const float* w_rec0 = (const float*)d_in[3];
    const float* w_in1 = (const float*)d_in[4];
    const float* w_rec1 = (const float*)d_in[5];
    float* out = (float*)d_out;

    // workspace carve (~51.5 MB total)
    float* xproj = (float*)d_ws;                   // NH f32 (20.48 MB)
    __bf16* stateA = (__bf16*)(xproj + NH);        // NH + HID bf16 (pad row)
    __bf16* stateB = stateA + NH + HID;            // NH + HID bf16 (pad row); x_bf first
    __bf16* packs = stateB + NH + HID;             // 4 x 16384 bf16
    int* deg = (int*)(packs + 4 * 16384);          // N
    int* ell = deg + N_NODES;                      // N*MAXW (10.24 MB)
    __bf16* pk_in0 = packs;
    __bf16* pk_rec0 = packs + 16384;
    __bf16* pk_in1 = packs + 2 * 16384;
    __bf16* pk_rec1 = packs + 3 * 16384;

    init_kernel<<<N_EDGES / 256, 256, 0, stream>>>(ell, deg, stateA + NH, stateB + NH);
    build_ell_kernel<<<N_EDGES / 256, 256, 0, stream>>>(ei, deg, ell);
    pack_w_kernel<<<64, 256, 0, stream>>>(w_in0, pk_in0, 1);   // B = w_in0^T
    pack_w_kernel<<<64, 256, 0, stream>>>(w_rec0, pk_rec0, 0); // B = w_rec0
    pack_w_kernel<<<64, 256, 0, stream>>>(w_in1, pk_in1, 1);
    pack_w_kernel<<<64, 256, 0, stream>>>(w_rec1, pk_rec1, 0);
    cast_bf16_kernel<<<NH / 4 / 256, 256, 0, stream>>>(x, stateB);  // x_bf in stateB

    for (int layer = 0; layer < 2; ++layer) {
        const __bf16* pk_in = layer ? pk_in1 : pk_in0;
        const __bf16* pk_rec = layer ? pk_rec1 : pk_rec0;
        // xproj = (layer ? h0 : x_bf) @ w_in^T ; stateA = tanh(xproj).
        // layer 0: A = stateB (x_bf). layer 1: A = stateA (h0) — aliased with
        // st_bf, safe (each wave reads only its own rows before storing them).
        const __bf16* xin = layer ? stateA : stateB;
        mfma_gemm_kernel<<<625, 256, 0, stream>>>(xin, pk_in, xproj, stateA);
        // 8 ping-pong iterations: A->B, B->A, ... ends in stateA.
        for (int it = 0; it < ITERS; ++it) {
            const __bf16* sin = (it & 1) ? stateB : stateA;
            __bf16* sout = (it & 1) ? stateA : stateB;
            float* f32out = (layer == 1 && it == ITERS - 1) ? out : nullptr;
            fused_iter_kernel<<<625, 256, 0, stream>>>(sin, sout, ell, deg,
                                                       pk_rec, xproj, f32out);
        }
    }
}

// Round 5
// 589.633 us; speedup vs baseline: 1.2521x; 1.2521x over previous
//
#include <hip/hip_runtime.h>
#include <math.h>

#define N_NODES 40000
#define N_EDGES 640000
#define HID 128
#define MAXW 64      // in-degree ~ Poisson(16); P(deg > 64) ~ 1e-19 -> never drops edges
#define ITERS 8      // full iterations after initial state = tanh(xproj)
#define NH (N_NODES * HID)

typedef __bf16 bf16x8 __attribute__((ext_vector_type(8)));
typedef __bf16 bf16x4 __attribute__((ext_vector_type(4)));
typedef float floatx4 __attribute__((ext_vector_type(4)));

// Fill ELL with pad index N_NODES, zero deg, zero the pad row of BOTH state buffers.
__global__ __launch_bounds__(256) void init_kernel(int* __restrict__ ell,
                                                   int* __restrict__ deg,
                                                   __bf16* __restrict__ padA,
                                                   __bf16* __restrict__ padB) {
    int i = blockIdx.x * 256 + threadIdx.x;   // N_EDGES threads
    int4 pad = {N_NODES, N_NODES, N_NODES, N_NODES};
    ((int4*)ell)[i] = pad;                    // N*MAXW/4 = 640000 int4 exactly
    if (i < N_NODES) deg[i] = 0;
    if (i < HID / 8) {
        bf16x8 z;
#pragma unroll
        for (int j = 0; j < 8; ++j) z[j] = (__bf16)0.f;
        ((bf16x8*)padA)[i] = z;
        ((bf16x8*)padB)[i] = z;
    }
}

__global__ __launch_bounds__(256) void build_ell_kernel(const int* __restrict__ ei,
                                                        int* __restrict__ deg,
                                                        int* __restrict__ ell) {
    int e = blockIdx.x * 256 + threadIdx.x;
    if (e >= N_EDGES) return;
    int s = ei[e];            // src
    int d = ei[N_EDGES + e];  // dst
    int c = atomicAdd(&deg[d], 1);
    if (c < MAXW) ell[d * MAXW + c] = s;
}

// Pack W (or W^T) into B-fragment order for mfma_f32_16x16x32_bf16:
// pk[((c*8+t)*64 + lane)*8 + j] = B[k = c*32 + (lane>>4)*8 + j][n = t*16 + (lane&15)]
__global__ __launch_bounds__(256) void pack_w_kernel(const float* __restrict__ w,
                                                     __bf16* __restrict__ pk, int trans) {
    int f = blockIdx.x * 256 + threadIdx.x;  // 16384 total
    int j = f & 7, l = (f >> 3) & 63, t = (f >> 9) & 7, c = f >> 12;
    int k = c * 32 + (l >> 4) * 8 + j;
    int n = t * 16 + (l & 15);
    float v = trans ? w[n * HID + k] : w[k * HID + n];
    pk[f] = (__bf16)v;
}

__global__ __launch_bounds__(256) void cast_bf16_kernel(const float* __restrict__ x,
                                                        __bf16* __restrict__ o) {
    int i = blockIdx.x * 256 + threadIdx.x;   // NH/4 threads
    float4 v = ((const float4*)x)[i];
    bf16x4 b;
    b[0] = (__bf16)v.x; b[1] = (__bf16)v.y; b[2] = (__bf16)v.z; b[3] = (__bf16)v.w;
    ((bf16x4*)o)[i] = b;
}

// Standalone GEMM for the xproj step (runs twice): out = A @ B (raw + tanh state).
__global__ __launch_bounds__(256) void mfma_gemm_kernel(const __bf16* A,
                                                        const __bf16* __restrict__ Bpk,
                                                        float* __restrict__ raw_out,
                                                        __bf16* st_bf) {
    __shared__ float tile[4][16][132];
    int tid = threadIdx.x;
    int wv = tid >> 6, lane = tid & 63;
    int q = lane >> 4, cl = lane & 15;

    int row_a = blockIdx.x * 64 + wv * 16 + cl;
    bf16x8 a[4];
#pragma unroll
    for (int c = 0; c < 4; ++c)
        a[c] = *(const bf16x8*)(A + (size_t)row_a * HID + c * 32 + q * 8);

#pragma unroll
    for (int t = 0; t < 8; ++t) {
        floatx4 acc_t = {0.f, 0.f, 0.f, 0.f};
#pragma unroll
        for (int c = 0; c < 4; ++c) {
            bf16x8 b = *(const bf16x8*)(Bpk + (((c * 8 + t) * 64 + lane) << 3));
            acc_t = __builtin_amdgcn_mfma_f32_16x16x32_bf16(a[c], b, acc_t, 0, 0, 0);
        }
#pragma unroll
        for (int r = 0; r < 4; ++r)
            tile[wv][q * 4 + r][t * 16 + cl] = acc_t[r];
    }
    int row = lane >> 2, seg = lane & 3;
    size_t goff = (size_t)(blockIdx.x * 64 + wv * 16 + row) * HID + seg * 32;
    float v[32];
#pragma unroll
    for (int j = 0; j < 8; ++j) {
        floatx4 t4 = *(floatx4*)&tile[wv][row][seg * 32 + j * 4];
        v[j * 4] = t4[0]; v[j * 4 + 1] = t4[1]; v[j * 4 + 2] = t4[2]; v[j * 4 + 3] = t4[3];
        float4 o = {t4[0], t4[1], t4[2], t4[3]};
        *(float4*)(raw_out + goff + j * 4) = o;   // xproj (pre-tanh)
    }
#pragma unroll
    for (int i = 0; i < 32; ++i) v[i] = tanhf(v[i]);
#pragma unroll
    for (int j = 0; j < 4; ++j) {
        bf16x8 o;
#pragma unroll
        for (int k = 0; k < 8; ++k) o[k] = (__bf16)v[j * 8 + k];
        *(bf16x8*)(st_bf + goff + j * 8) = o;
    }
}

// Fused iteration v2: state_out = tanh(xproj + gather(state_in) @ W).
// 32 nodes/block, 1250 blocks (~19.5 waves/CU; round 4's 625x4 gave only ~10
// and the latency-bound gather collapsed). Gather v3: block's padded ELL rows
// staged to LDS; each 16-lane quarter owns 2 whole nodes (no cross-quarter
// butterfly, no ds_bpermute; index reads are same-address LDS broadcasts),
// interleaving the 2 nodes for 8 outstanding 16B loads. Pad slots hit the
// zero row -> no masking in the hot loop.
// LDS: ell(8704) + aggr(8704) overlaid by epilogue tile (17408) -> 17.4 KB.
__global__ __launch_bounds__(256) void fused_iter_kernel(
    const __bf16* __restrict__ state_in,
    __bf16* __restrict__ state_out,
    const int* __restrict__ ell,
    const int* __restrict__ deg,
    const __bf16* __restrict__ Bpk,
    const float* __restrict__ xproj,
    float* __restrict__ st_f32) {
    __shared__ __align__(16) char smem[17408];
    int(*ell_lds)[68] = (int(*)[68])smem;                    // [32][68] int: 8704 B
    __bf16(*aggr_lds)[136] = (__bf16(*)[136])(smem + 8704);  // [32][136] bf16: 8704 B
    float(*tile)[16][68] = (float(*)[16][68])smem;           // [4][16][68] f32: 17408 B

    int tid = threadIdx.x;
    int wv = tid >> 6, lane = tid & 63;
    int q = lane >> 4, f = lane & 15;
    int nb = blockIdx.x * 32;

    // stage ELL: 32 rows x 64 ints = 512 int4, 2 per thread (row stride 68 -> +4
    // int pad: staggers banks for the 4-address broadcast reads below)
#pragma unroll
    for (int i = 0; i < 2; ++i) {
        int g = tid * 2 + i;
        int n = g >> 4, c = (g & 15) << 2;
        int4 v = *(const int4*)&ell[(nb + n) * MAXW + c];
        *(int4*)&ell_lds[n][c] = v;
    }
    int degv = deg[nb + (lane & 31)];
    __syncthreads();

    // ---- phase 1: quarter q of wave wv aggregates nodes wv*8+q and wv*8+4+q ----
    int n0 = wv * 8 + q;
    int n1 = wv * 8 + 4 + q;
    int cnt0 = __shfl(degv, n0); if (cnt0 > MAXW) cnt0 = MAXW;
    int cnt1 = __shfl(degv, n1); if (cnt1 > MAXW) cnt1 = MAXW;
    int ga = (cnt0 + 3) >> 2, gb = (cnt1 + 3) >> 2;
    int gmax = ga > gb ? ga : gb;
    float acc0[8], acc1[8];
#pragma unroll
    for (int j = 0; j < 8; ++j) { acc0[j] = 0.f; acc1[j] = 0.f; }
    for (int g = 0; g < gmax; ++g) {
        int base = g * 4;
        int sA0 = ell_lds[n0][base + 0];
        int sA1 = ell_lds[n0][base + 1];
        int sA2 = ell_lds[n0][base + 2];
        int sA3 = ell_lds[n0][base + 3];
        int sB0 = ell_lds[n1][base + 0];
        int sB1 = ell_lds[n1][base + 1];
        int sB2 = ell_lds[n1][base + 2];
        int sB3 = ell_lds[n1][base + 3];
        bf16x8 vA0 = *(const bf16x8*)(state_in + (size_t)sA0 * HID + f * 8);
        bf16x8 vA1 = *(const bf16x8*)(state_in + (size_t)sA1 * HID + f * 8);
        bf16x8 vA2 = *(const bf16x8*)(state_in + (size_t)sA2 * HID + f * 8);
        bf16x8 vA3 = *(const bf16x8*)(state_in + (size_t)sA3 * HID + f * 8);
        bf16x8 vB0 = *(const bf16x8*)(state_in + (size_t)sB0 * HID + f * 8);
        bf16x8 vB1 = *(const bf16x8*)(state_in + (size_t)sB1 * HID + f * 8);
        bf16x8 vB2 = *(const bf16x8*)(state_in + (size_t)sB2 * HID + f * 8);
        bf16x8 vB3 = *(const bf16x8*)(state_in + (size_t)sB3 * HID + f * 8);
#pragma unroll
        for (int j = 0; j < 8; ++j) {
            acc0[j] += ((float)vA0[j] + (float)vA1[j]) + ((float)vA2[j] + (float)vA3[j]);
            acc1[j] += ((float)vB0[j] + (float)vB1[j]) + ((float)vB2[j] + (float)vB3[j]);
        }
    }
    {
        bf16x8 o0, o1;
#pragma unroll
        for (int j = 0; j < 8; ++j) { o0[j] = (__bf16)acc0[j]; o1[j] = (__bf16)acc1[j]; }
        *(bf16x8*)&aggr_lds[n0][f * 8] = o0;
        *(bf16x8*)&aggr_lds[n1][f * 8] = o1;
    }
    __syncthreads();

    // ---- phase 2: waves {0,1}->rows 0-15, {2,3}->rows 16-31; h=wv&1 -> col half ----
    int rg = wv >> 1, h = wv & 1;
    bf16x8 a[4];
#pragma unroll
    for (int c = 0; c < 4; ++c)
        a[c] = *(const bf16x8*)&aggr_lds[rg * 16 + f][c * 32 + q * 8];
    __syncthreads();   // overlay safety: all aggr/ell reads done before tile writes

#pragma unroll
    for (int t = 0; t < 4; ++t) {
        floatx4 acc_t = {0.f, 0.f, 0.f, 0.f};
#pragma unroll
        for (int c = 0; c < 4; ++c) {
            bf16x8 b = *(const bf16x8*)(Bpk + (((c * 8 + h * 4 + t) * 64 + lane) << 3));
            acc_t = __builtin_amdgcn_mfma_f32_16x16x32_bf16(a[c], b, acc_t, 0, 0, 0);
        }
#pragma unroll
        for (int r = 0; r < 4; ++r)
            tile[wv][q * 4 + r][t * 16 + f] = acc_t[r];
    }

    // epilogue: wave covers rows rg*16..+15, global cols h*64..+63 (16 floats/lane)
    int row = lane >> 2, seg = lane & 3;
    size_t goff = (size_t)(nb + rg * 16 + row) * HID + h * 64 + seg * 16;
    float v[16];
#pragma unroll
    for (int j = 0; j < 4; ++j) {
        floatx4 t4 = *(floatx4*)&tile[wv][row][seg * 16 + j * 4];
        float4 b = *(const float4*)(xproj + goff + j * 4);
        v[j * 4] = t4[0] + b.x;
        v[j * 4 + 1] = t4[1] + b.y;
        v[j * 4 + 2] = t4[2] + b.z;
        v[j * 4 + 3] = t4[3] + b.w;
    }
#pragma unroll
    for (int i = 0; i < 16; ++i) v[i] = tanhf(v[i]);
#pragma unroll
    for (int j = 0; j < 2; ++j) {
        bf16x8 o;
#pragma unroll
        for (int k = 0; k < 8; ++k) o[k] = (__bf16)v[j * 8 + k];
        *(bf16x8*)(state_out + goff + j * 8) = o;
    }
    if (st_f32) {
#pragma unroll
        for (int j = 0; j < 4; ++j) {
            float4 o = {v[j * 4], v[j * 4 + 1], v[j * 4 + 2], v[j * 4 + 3]};
            *(float4*)(st_f32 + goff + j * 4) = o;
        }
    }
}

extern "C" void kernel_launch(void* const* d_in, const int* in_sizes, int n_in,
                              void* d_out, int out_size, void* d_ws, size_t ws_size,
                              hipStream_t stream) {
    const int* ei = (const int*)d_in[0];       // edge_index [2][E]
    const float* x = (const float*)d_in[1];    // [N][128] f32
    const float* w_in0 = (const float*)d_in[2];
    const float* w_rec0 = (const float*)d_in[3];
    const float* w_in1 = (const float*)d_in[4];
    const float* w_rec1 = (const float*)d_in[5];
    float* out = (float*)d_out;

    // workspace carve (~51.5 MB total)
    float* xproj = (float*)d_ws;                   // NH f32 (20.48 MB)
    __bf16* stateA = (__bf16*)(xproj + NH);        // NH + HID bf16 (pad row)
    __bf16* stateB = stateA + NH + HID;            // NH + HID bf16 (pad row); x_bf first
    __bf16* packs = stateB + NH + HID;             // 4 x 16384 bf16
    int* deg = (int*)(packs + 4 * 16384);          // N
    int* ell = deg + N_NODES;                      // N*MAXW (10.24 MB)
    __bf16* pk_in0 = packs;
    __bf16* pk_rec0 = packs + 16384;
    __bf16* pk_in1 = packs + 2 * 16384;
    __bf16* pk_rec1 = packs + 3 * 16384;

    init_kernel<<<N_EDGES / 256, 256, 0, stream>>>(ell, deg, stateA + NH, stateB + NH);
    build_ell_kernel<<<N_EDGES / 256, 256, 0, stream>>>(ei, deg, ell);
    pack_w_kernel<<<64, 256, 0, stream>>>(w_in0, pk_in0, 1);   // B = w_in0^T
    pack_w_kernel<<<64, 256, 0, stream>>>(w_rec0, pk_rec0, 0); // B = w_rec0
    pack_w_kernel<<<64, 256, 0, stream>>>(w_in1, pk_in1, 1);
    pack_w_kernel<<<64, 256, 0, stream>>>(w_rec1, pk_rec1, 0);
    cast_bf16_kernel<<<NH / 4 / 256, 256, 0, stream>>>(x, stateB);  // x_bf in stateB

    for (int layer = 0; layer < 2; ++layer) {
        const __bf16* pk_in = layer ? pk_in1 : pk_in0;
        const __bf16* pk_rec = layer ? pk_rec1 : pk_rec0;
        // xproj = (layer ? h0 : x_bf) @ w_in^T ; stateA = tanh(xproj).
        const __bf16* xin = layer ? stateA : stateB;
        mfma_gemm_kernel<<<625, 256, 0, stream>>>(xin, pk_in, xproj, stateA);
        // 8 ping-pong iterations: A->B, B->A, ... ends in stateA.
        for (int it = 0; it < ITERS; ++it) {
            const __bf16* sin = (it & 1) ? stateB : stateA;
            __bf16* sout = (it & 1) ? stateA : stateB;
            float* f32out = (layer == 1 && it == ITERS - 1) ? out : nullptr;
            fused_iter_kernel<<<N_NODES / 32, 256, 0, stream>>>(sin, sout, ell, deg,
                                                                pk_rec, xproj, f32out);
        }
    }
}